// Round 9
// baseline (370.926 us; speedup 1.0000x reference)
//
#include <hip/hip_runtime.h>

// SimpleNet R9: MFMA f16 matmuls (R5 layout) + packed-fp16 Padé tanh forced
// via inline-asm VOP3P (R8's builtins scalarized; R7 proved asm sticks).
//   tanh x = x(s^2+105s+945)/(15s^2+420s+945), s=x^2, clamp |x|<=3.625
// Division: fp16 bit-trick seed via ONE v_sub_u32 (0x77997799 - bits; den bits
// in [0x6362,0x706C] so no cross-half borrow) + 2 packed Newton.
// Sigmoid = 0.5 + 0.5*tanh(y/2), 0.5 folded into w_out. Numerics validated R8.

#define HW_PIX (1024 * 1024)
#define HID    25

typedef __fp16 h8 __attribute__((ext_vector_type(8)));
typedef __fp16 h2 __attribute__((ext_vector_type(2)));
typedef float  f32x4 __attribute__((ext_vector_type(4)));

#define WS_WINP_BYTE 13312

__device__ __forceinline__ int mu_map(int k) {
    int g = k >> 3, j = k & 7;
    return (j < 4) ? (4 * g + j) : (16 + 4 * g + (j & 3));
}

__global__ __launch_bounds__(256) void prep_kernel(
    const float* __restrict__ w_in, const float* __restrict__ ws,
    const float* __restrict__ w_out, __fp16* __restrict__ wsA,
    float* __restrict__ winp)
{
    int tid = threadIdx.x;
    for (int u = tid; u < 12 * 64; u += 256) {
        int q = u & 63, combo = u >> 6;
        int l = combo >> 1, t = combo & 1;
        int m = t * 16 + (q & 15);
        for (int j = 0; j < 8; ++j) {
            int k = (q >> 4) * 8 + j;
            int c = mu_map(k);
            float v = (m < HID && c < HID) ? ws[(l * HID + m) * HID + c] : 0.0f;
            wsA[u * 8 + j] = (__fp16)v;
        }
    }
    if (tid < 64) {
        int q = tid, m = q & 15;
        for (int j = 0; j < 8; ++j) {
            int k = (q >> 4) * 8 + j;
            int c = mu_map(k);
            float v = (m < 3 && c < HID) ? w_out[m * HID + c] * 0.5f : 0.0f;
            wsA[(12 * 64 + q) * 8 + j] = (__fp16)v;
        }
    }
    if (tid < 32) {
        int k = tid, c = mu_map(k);
        for (int ci = 0; ci < 3; ++ci)
            winp[k * 3 + ci] = (c < HID) ? w_in[c * 3 + ci] : 0.0f;
    }
}

// ---- forced VOP3P packed-fp16 ops ----
__device__ __forceinline__ h2 pk_max(h2 a, h2 b) {
    h2 d; asm("v_pk_max_f16 %0, %1, %2" : "=v"(d) : "v"(a), "v"(b)); return d;
}
__device__ __forceinline__ h2 pk_min(h2 a, h2 b) {
    h2 d; asm("v_pk_min_f16 %0, %1, %2" : "=v"(d) : "v"(a), "v"(b)); return d;
}
__device__ __forceinline__ h2 pk_add(h2 a, h2 b) {
    h2 d; asm("v_pk_add_f16 %0, %1, %2" : "=v"(d) : "v"(a), "v"(b)); return d;
}
__device__ __forceinline__ h2 pk_mul(h2 a, h2 b) {
    h2 d; asm("v_pk_mul_f16 %0, %1, %2" : "=v"(d) : "v"(a), "v"(b)); return d;
}
__device__ __forceinline__ h2 pk_fma(h2 a, h2 b, h2 c) {
    h2 d; asm("v_pk_fma_f16 %0, %1, %2, %3" : "=v"(d) : "v"(a), "v"(b), "v"(c)); return d;
}

// fp16 tanh constants, pinned in VGPRs once
struct HK {
    h2 C, nC, c105, c945, c15, c420, two, m1;
    unsigned magic;
};
__device__ __forceinline__ HK make_hk() {
    HK k;
    k.C    = (h2)(__fp16)3.625f;
    k.nC   = (h2)(__fp16)(-3.625f);
    k.c105 = (h2)(__fp16)105.0f;
    k.c945 = (h2)(__fp16)945.0f;
    k.c15  = (h2)(__fp16)15.0f;
    k.c420 = (h2)(__fp16)420.0f;
    k.two  = (h2)(__fp16)2.0f;
    k.m1   = (h2)(__fp16)(-1.0f);
    k.magic = 0x77997799u;
    asm("" : "+v"(k.C), "+v"(k.nC), "+v"(k.c105), "+v"(k.c945));
    asm("" : "+v"(k.c15), "+v"(k.c420), "+v"(k.two), "+v"(k.m1), "+v"(k.magic));
    return k;
}

// packed fp16 tanh: 2 evals, 15 VALU insts, all full-rate
__device__ __forceinline__ h2 tanh_h2(h2 z, const HK& k) {
    h2 x = pk_min(pk_max(z, k.nC), k.C);
    h2 s = pk_mul(x, x);
    h2 n = pk_fma(pk_add(s, k.c105), s, k.c945);   // s^2+105s+945
    n = pk_mul(n, x);
    h2 d = pk_fma(k.c15, s, k.c420);
    d = pk_fma(d, s, k.c945);                       // 15s^2+420s+945
    union { h2 h; unsigned u; } du, yu;
    du.h = d;
    unsigned su;
    asm("v_sub_u32 %0, %1, %2" : "=v"(su) : "v"(k.magic), "v"(du.u));
    yu.u = su;
    h2 y = yu.h;
    h2 nd = pk_mul(d, k.m1);
    h2 t = pk_fma(nd, y, k.two);                    // Newton x2
    y = pk_mul(y, t);
    t = pk_fma(nd, y, k.two);
    y = pk_mul(y, t);
    return pk_mul(n, y);
}

__global__ __launch_bounds__(256, 1) void simplenet_kernel(
    const float* __restrict__ x,
    const h8* __restrict__ wsA,
    const float* __restrict__ winp,
    float* __restrict__ out)
{
    const int lane = threadIdx.x & 63;
    const int wgid = blockIdx.x * 4 + (threadIdx.x >> 6);
    const int g = lane >> 4, col = lane & 15;

    const HK k = make_hk();

    h8 A[12];
#pragma unroll
    for (int i = 0; i < 12; ++i) A[i] = wsA[i * 64 + lane];
    h8 Aout = wsA[12 * 64 + lane];

    float wi[24];
    {
        const f32x4* wp4 = (const f32x4*)(winp + 8 * g * 3);
#pragma unroll
        for (int i = 0; i < 6; ++i) {
            f32x4 v = wp4[i];
            wi[i * 4 + 0] = v.x; wi[i * 4 + 1] = v.y; wi[i * 4 + 2] = v.z; wi[i * 4 + 3] = v.w;
        }
    }

    const int pbase = wgid * 512;
    const int b = pbase >> 20;
    const int hwb = pbase & (HW_PIX - 1);
    const float* xb = x + (size_t)b * 3 * HW_PIX;
    float* ob = out + (size_t)b * 3 * HW_PIX;

    for (int it = 0; it < 16; ++it) {
        const int hw0 = hwb + it * 32;

        // ---- input layer: fp32 fma, pack pre-acts, packed tanh ----
        h8 B[2];
#pragma unroll
        for (int n = 0; n < 2; ++n) {
            const int hw = hw0 + n * 16 + col;
            float x0 = xb[0 * HW_PIX + hw];
            float x1 = xb[1 * HW_PIX + hw];
            float x2 = xb[2 * HW_PIX + hw];
            float th[8];
#pragma unroll
            for (int j = 0; j < 8; ++j) {
                float acc = wi[j * 3 + 0] * x0;
                acc = fmaf(wi[j * 3 + 1], x1, acc);
                acc = fmaf(wi[j * 3 + 2], x2, acc);
                th[j] = acc;
            }
            union { h8 v; h2 p[4]; } u;
#pragma unroll
            for (int pr = 0; pr < 4; ++pr)
                u.p[pr] = tanh_h2(__builtin_amdgcn_cvt_pkrtz(th[pr * 2], th[pr * 2 + 1]), k);
            B[n] = u.v;
        }

        // ---- 6 hidden layers ----
#pragma unroll
        for (int l = 0; l < 6; ++l) {
#pragma unroll
            for (int n = 0; n < 2; ++n) {
                f32x4 zero = {0.0f, 0.0f, 0.0f, 0.0f};
                f32x4 d0 = __builtin_amdgcn_mfma_f32_16x16x32_f16(A[l * 2 + 0], B[n], zero, 0, 0, 0);
                f32x4 d1 = __builtin_amdgcn_mfma_f32_16x16x32_f16(A[l * 2 + 1], B[n], zero, 0, 0, 0);
                union { h8 v; h2 p[4]; } u;
                u.p[0] = tanh_h2(__builtin_amdgcn_cvt_pkrtz(d0.x, d0.y), k);
                u.p[1] = tanh_h2(__builtin_amdgcn_cvt_pkrtz(d0.z, d0.w), k);
                u.p[2] = tanh_h2(__builtin_amdgcn_cvt_pkrtz(d1.x, d1.y), k);
                u.p[3] = tanh_h2(__builtin_amdgcn_cvt_pkrtz(d1.z, d1.w), k);
                B[n] = u.v;
            }
        }

        // ---- output: sigmoid via pre-halved w_out + packed tanh ----
#pragma unroll
        for (int n = 0; n < 2; ++n) {
            f32x4 zero = {0.0f, 0.0f, 0.0f, 0.0f};
            f32x4 d = __builtin_amdgcn_mfma_f32_16x16x32_f16(Aout, B[n], zero, 0, 0, 0);
            if (g == 0) {
                h2 ta = tanh_h2(__builtin_amdgcn_cvt_pkrtz(d.x, d.y), k);
                h2 tb = tanh_h2(__builtin_amdgcn_cvt_pkrtz(d.z, d.z), k);
                const int hw = hw0 + n * 16 + col;
                ob[0 * HW_PIX + hw] = fmaf(0.5f, (float)ta.x, 0.5f);
                ob[1 * HW_PIX + hw] = fmaf(0.5f, (float)ta.y, 0.5f);
                ob[2 * HW_PIX + hw] = fmaf(0.5f, (float)tb.x, 0.5f);
            }
        }
    }
}

extern "C" void kernel_launch(void* const* d_in, const int* in_sizes, int n_in,
                              void* d_out, int out_size, void* d_ws, size_t ws_size,
                              hipStream_t stream) {
    const float* x     = (const float*)d_in[0];
    const float* w_in  = (const float*)d_in[1];
    const float* ws    = (const float*)d_in[2];
    const float* w_out = (const float*)d_in[3];
    float* out         = (float*)d_out;

    __fp16* wsA = (__fp16*)d_ws;
    float* winp = (float*)((char*)d_ws + WS_WINP_BYTE);

    hipLaunchKernelGGL(prep_kernel, dim3(1), dim3(256), 0, stream,
                       w_in, ws, w_out, wsA, winp);

    hipLaunchKernelGGL(simplenet_kernel, dim3(2048), dim3(256), 0, stream,
                       x, (const h8*)d_ws, winp, out);
}

// Round 10
// 313.577 us; speedup vs baseline: 1.1829x; 1.1829x over previous
//
#include <hip/hip_runtime.h>

// SimpleNet R10: R5 (measured-best: exp2/rcp tanh, scales folded) restructured
// to amortize per-iteration overhead:
//  - 4 N-tiles (64 px) per wave-iter, 8 iters (was 2 N-tiles x 16 iters)
//  - A-fragments / input-weights / zero-C pinned in VGPRs via empty-asm:
//    asm-defined values cannot be rematerialized or re-loaded, so the 16x
//    unrolled body stops re-fetching A and re-materializing the zero quad
//    (R5-R9 all sat at VGPR 56-68 => compiler was reloading per use).
//  - no ",1" in launch_bounds (occupancy confound since R2).
// MFMA layout validated R5-R9: mu(k) relabeling makes D regs == next B elems.

#define HW_PIX (1024 * 1024)
#define HID    25

#define TANH_SCALE 2.8853900817779268f    // 2*log2(e)
#define SIG_SCALE  (-1.4426950408889634f) // -log2(e)

typedef __fp16 h8 __attribute__((ext_vector_type(8)));
typedef __fp16 h2 __attribute__((ext_vector_type(2)));
typedef float f32x4 __attribute__((ext_vector_type(4)));

#define WS_WINP_BYTE 13312

__device__ __forceinline__ int mu_map(int k) {
    int g = k >> 3, j = k & 7;
    return (j < 4) ? (4 * g + j) : (16 + 4 * g + (j & 3));
}

__global__ __launch_bounds__(256) void prep_kernel(
    const float* __restrict__ w_in, const float* __restrict__ ws,
    const float* __restrict__ w_out, __fp16* __restrict__ wsA,
    float* __restrict__ winp)
{
    int tid = threadIdx.x;
    for (int u = tid; u < 12 * 64; u += 256) {
        int q = u & 63, combo = u >> 6;
        int l = combo >> 1, t = combo & 1;
        int m = t * 16 + (q & 15);
        for (int j = 0; j < 8; ++j) {
            int k = (q >> 4) * 8 + j;
            int c = mu_map(k);
            float v = (m < HID && c < HID) ? ws[(l * HID + m) * HID + c] * TANH_SCALE : 0.0f;
            wsA[u * 8 + j] = (__fp16)v;
        }
    }
    if (tid < 64) {
        int q = tid, m = q & 15;
        for (int j = 0; j < 8; ++j) {
            int k = (q >> 4) * 8 + j;
            int c = mu_map(k);
            float v = (m < 3 && c < HID) ? w_out[m * HID + c] * SIG_SCALE : 0.0f;
            wsA[(12 * 64 + q) * 8 + j] = (__fp16)v;
        }
    }
    if (tid < 32) {
        int k = tid, c = mu_map(k);
        for (int ci = 0; ci < 3; ++ci)
            winp[k * 3 + ci] = (c < HID) ? w_in[c * 3 + ci] * TANH_SCALE : 0.0f;
    }
}

__device__ __forceinline__ float tanh_scaled(float acc) {   // acc = 2log2e * z
    float e = __builtin_amdgcn_exp2f(acc);
    float r = __builtin_amdgcn_rcpf(e + 1.0f);
    return fmaf(-2.0f, r, 1.0f);
}
__device__ __forceinline__ float sig_scaled(float acc) {    // acc = -log2e * z
    float e = __builtin_amdgcn_exp2f(acc);
    return __builtin_amdgcn_rcpf(e + 1.0f);
}

__global__ __launch_bounds__(256) void simplenet_kernel(
    const float* __restrict__ x,
    const h8* __restrict__ wsA,
    const float* __restrict__ winp,
    float* __restrict__ out)
{
    const int lane = threadIdx.x & 63;
    const int wgid = blockIdx.x * 4 + (threadIdx.x >> 6);
    const int g = lane >> 4, col = lane & 15;

    // weight fragments: load once, PIN so they cannot be re-loaded per iter
    h8 A[12];
#pragma unroll
    for (int i = 0; i < 12; ++i) A[i] = wsA[i * 64 + lane];
    h8 Aout = wsA[12 * 64 + lane];
    asm("" : "+v"(A[0]), "+v"(A[1]), "+v"(A[2]), "+v"(A[3]));
    asm("" : "+v"(A[4]), "+v"(A[5]), "+v"(A[6]), "+v"(A[7]));
    asm("" : "+v"(A[8]), "+v"(A[9]), "+v"(A[10]), "+v"(A[11]), "+v"(Aout));

    f32x4 wiv[6];
    {
        const f32x4* wp4 = (const f32x4*)(winp + 8 * g * 3);
#pragma unroll
        for (int i = 0; i < 6; ++i) wiv[i] = wp4[i];
    }
    asm("" : "+v"(wiv[0]), "+v"(wiv[1]), "+v"(wiv[2]));
    asm("" : "+v"(wiv[3]), "+v"(wiv[4]), "+v"(wiv[5]));
    float wi[24];
#pragma unroll
    for (int i = 0; i < 6; ++i) {
        wi[i * 4 + 0] = wiv[i].x; wi[i * 4 + 1] = wiv[i].y;
        wi[i * 4 + 2] = wiv[i].z; wi[i * 4 + 3] = wiv[i].w;
    }

    // one pinned zero accumulator quad (stop per-MFMA zero remat)
    f32x4 zero = {0.0f, 0.0f, 0.0f, 0.0f};
    asm("" : "+v"(zero));

    const int pbase = wgid * 512;
    const int b = pbase >> 20;
    const int hwb = pbase & (HW_PIX - 1);
    const float* xb = x + (size_t)b * 3 * HW_PIX;
    float* ob = out + (size_t)b * 3 * HW_PIX;

    for (int it = 0; it < 8; ++it) {
        const int hw0 = hwb + it * 64;

        // ---- input layer: 4 N-tiles ----
        h8 B[4];
#pragma unroll
        for (int n = 0; n < 4; ++n) {
            const int hw = hw0 + n * 16 + col;
            float x0 = xb[0 * HW_PIX + hw];
            float x1 = xb[1 * HW_PIX + hw];
            float x2 = xb[2 * HW_PIX + hw];
            float th[8];
#pragma unroll
            for (int j = 0; j < 8; ++j) {
                float acc = wi[j * 3 + 0] * x0;
                acc = fmaf(wi[j * 3 + 1], x1, acc);
                acc = fmaf(wi[j * 3 + 2], x2, acc);
                th[j] = tanh_scaled(acc);
            }
            union { h8 v; h2 p[4]; } u;
#pragma unroll
            for (int pr = 0; pr < 4; ++pr)
                u.p[pr] = __builtin_amdgcn_cvt_pkrtz(th[pr * 2], th[pr * 2 + 1]);
            B[n] = u.v;
        }

        // ---- 6 hidden layers x 4 N-tiles ----
#pragma unroll
        for (int l = 0; l < 6; ++l) {
#pragma unroll
            for (int n = 0; n < 4; ++n) {
                f32x4 d0 = __builtin_amdgcn_mfma_f32_16x16x32_f16(A[l * 2 + 0], B[n], zero, 0, 0, 0);
                f32x4 d1 = __builtin_amdgcn_mfma_f32_16x16x32_f16(A[l * 2 + 1], B[n], zero, 0, 0, 0);
                union { h8 v; h2 p[4]; } u;
                u.p[0] = __builtin_amdgcn_cvt_pkrtz(tanh_scaled(d0.x), tanh_scaled(d0.y));
                u.p[1] = __builtin_amdgcn_cvt_pkrtz(tanh_scaled(d0.z), tanh_scaled(d0.w));
                u.p[2] = __builtin_amdgcn_cvt_pkrtz(tanh_scaled(d1.x), tanh_scaled(d1.y));
                u.p[3] = __builtin_amdgcn_cvt_pkrtz(tanh_scaled(d1.z), tanh_scaled(d1.w));
                B[n] = u.v;
            }
        }

        // ---- output layer ----
#pragma unroll
        for (int n = 0; n < 4; ++n) {
            f32x4 d = __builtin_amdgcn_mfma_f32_16x16x32_f16(Aout, B[n], zero, 0, 0, 0);
            if (g == 0) {
                const int hw = hw0 + n * 16 + col;
                ob[0 * HW_PIX + hw] = sig_scaled(d.x);
                ob[1 * HW_PIX + hw] = sig_scaled(d.y);
                ob[2 * HW_PIX + hw] = sig_scaled(d.z);
            }
        }
    }
}

extern "C" void kernel_launch(void* const* d_in, const int* in_sizes, int n_in,
                              void* d_out, int out_size, void* d_ws, size_t ws_size,
                              hipStream_t stream) {
    const float* x     = (const float*)d_in[0];
    const float* w_in  = (const float*)d_in[1];
    const float* ws    = (const float*)d_in[2];
    const float* w_out = (const float*)d_in[3];
    float* out         = (float*)d_out;

    __fp16* wsA = (__fp16*)d_ws;
    float* winp = (float*)((char*)d_ws + WS_WINP_BYTE);

    hipLaunchKernelGGL(prep_kernel, dim3(1), dim3(256), 0, stream,
                       w_in, ws, w_out, wsA, winp);

    // 2048 blocks x 4 waves x 8 iters x 64 px = 4Mi pixels, exact
    hipLaunchKernelGGL(simplenet_kernel, dim3(2048), dim3(256), 0, stream,
                       x, (const h8*)d_ws, winp, out);
}